// Round 1
// baseline (2417.785 us; speedup 1.0000x reference)
//
#include <hip/hip_runtime.h>

// SemaEmb GIN network, fp32 baseline.
// N=100000 (div by 32), E=1600000, EMB=128, L=3, P=4, tables 64 entries.

#define EMBD 128
#define PADLD 132   // LDS leading-dim pad: 132%4==0 (float4 aligned), 132%32==4 (bank spread)

__device__ __forceinline__ float lrelu(float x) { return x > 0.0f ? x : 0.01f * x; }

// ---------------- table folding: A[t][v][j] = emb_t[v] @ W1_rows[t*128 .. t*128+128) ----------
__global__ void tables_kernel(const float* __restrict__ opT, const float* __restrict__ parT,
                              const float* __restrict__ W1, float* __restrict__ A)
{
    int b = blockIdx.x;            // 0..319 : t*64+v
    int t = b >> 6, v = b & 63, j = threadIdx.x;
    const float* emb = (t == 0 ? opT : parT) + v * EMBD;
    const float* w = W1 + (size_t)t * EMBD * EMBD;
    float acc = 0.f;
    for (int k = 0; k < EMBD; ++k) acc += emb[k] * w[k * EMBD + j];
    A[(size_t)b * EMBD + j] = acc;
}

// ---------------- CSR build ----------------
__global__ void count_kernel(const int* __restrict__ src, const int* __restrict__ dst,
                             int* __restrict__ cnt_f, int* __restrict__ cnt_i, int e)
{
    int t = blockIdx.x * 256 + threadIdx.x;
    if (t >= e) return;
    atomicAdd(&cnt_f[dst[t]], 1);
    atomicAdd(&cnt_i[src[t]], 1);
}

// single-block exclusive scan (2 blocks: fwd & inv arrays)
__global__ void scan_kernel(const int* __restrict__ c0, int* __restrict__ o0,
                            const int* __restrict__ c1, int* __restrict__ o1, int n)
{
    const int* cnt = blockIdx.x ? c1 : c0;
    int* offs = blockIdx.x ? o1 : o0;
    __shared__ int wtot[16];
    __shared__ int carry;
    int tid = threadIdx.x;
    int lane = tid & 63, wv = tid >> 6;
    if (tid == 0) carry = 0;
    __syncthreads();
    for (int base = 0; base < n; base += 1024) {
        int i = base + tid;
        int v = (i < n) ? cnt[i] : 0;
        int incl = v;
        #pragma unroll
        for (int s = 1; s < 64; s <<= 1) {
            int t = __shfl_up(incl, s, 64);
            if (lane >= s) incl += t;
        }
        if (lane == 63) wtot[wv] = incl;
        __syncthreads();
        if (tid == 0) {
            int run = 0;
            #pragma unroll
            for (int q = 0; q < 16; ++q) { int t = wtot[q]; wtot[q] = run; run += t; }
        }
        __syncthreads();
        if (i < n) offs[i] = carry + wtot[wv] + incl - v;
        __syncthreads();
        if (tid == 1023) carry += wtot[15] + incl;   // incl of tid1023 == wave15 total
        __syncthreads();
    }
}

__global__ void fill_kernel(const int* __restrict__ src, const int* __restrict__ dst,
                            const int* __restrict__ off_f, const int* __restrict__ off_i,
                            int* __restrict__ cur_f, int* __restrict__ cur_i,
                            int* __restrict__ csr_f, int* __restrict__ csr_i, int e)
{
    int t = blockIdx.x * 256 + threadIdx.x;
    if (t >= e) return;
    int s = src[t], d = dst[t];
    int p = atomicAdd(&cur_f[d], 1);
    csr_f[off_f[d] + p] = s;
    int q = atomicAdd(&cur_i[s], 1);
    csr_i[off_i[s] + q] = d;
}

// ---------------- aggregation: msg[i] = S[i] + mean_{nbr in csr[i]} S[nbr] ----------------
__global__ __launch_bounds__(256) void agg_kernel(
    const float* __restrict__ S, const int* __restrict__ csr,
    const int* __restrict__ offs, const int* __restrict__ cnt,
    float* __restrict__ msg, int n)
{
    int gw = (blockIdx.x * 256 + threadIdx.x) >> 6;   // one wave per node
    int lane = threadIdx.x & 63;
    if (gw >= n) return;
    int off = offs[gw], deg = cnt[gw];
    const float2* Sp = (const float2*)S;
    float ax = 0.f, ay = 0.f;
    int d = 0;
    for (; d + 4 <= deg; d += 4) {
        int n0 = csr[off + d + 0], n1 = csr[off + d + 1];
        int n2 = csr[off + d + 2], n3 = csr[off + d + 3];
        float2 v0 = Sp[(size_t)n0 * 64 + lane];
        float2 v1 = Sp[(size_t)n1 * 64 + lane];
        float2 v2 = Sp[(size_t)n2 * 64 + lane];
        float2 v3 = Sp[(size_t)n3 * 64 + lane];
        ax += (v0.x + v1.x) + (v2.x + v3.x);
        ay += (v0.y + v1.y) + (v2.y + v3.y);
    }
    for (; d < deg; ++d) {
        int nn = csr[off + d];
        float2 v = Sp[(size_t)nn * 64 + lane];
        ax += v.x; ay += v.y;
    }
    float invd = 1.0f / fmaxf((float)deg, 1.0f);
    float2 own = Sp[(size_t)gw * 64 + lane];
    float2 o;
    o.x = own.x + ax * invd;
    o.y = own.y + ay * invd;
    ((float2*)msg)[(size_t)gw * 64 + lane] = o;
}

// ---------------- shared GEMM core: out_rows(32) x 128, K=128, W staged in 64-row halves ----
__device__ __forceinline__ void stage_rows(const float* __restrict__ src,
                                           float* __restrict__ lds_in, int node0, int tid)
{
    for (int q = tid; q < 1024; q += 256) {
        int r = q >> 5, c4 = q & 31;
        float4 v = ((const float4*)src)[(size_t)(node0 + r) * 32 + c4];
        *(float4*)&lds_in[r * PADLD + c4 * 4] = v;
    }
}

__device__ __forceinline__ void gemm_core_128(
    float* __restrict__ lds_w, const float* __restrict__ lds_in,
    const float* __restrict__ Wg, float acc[4][4], int tid)
{
    int ty = tid >> 5, tx = tid & 31;
    for (int p = 0; p < 2; ++p) {
        __syncthreads();                               // in-tile ready / prev pass done
        const float4* wsrc = (const float4*)(Wg + (size_t)p * 64 * EMBD);
        float4* wdst = (float4*)lds_w;
        #pragma unroll
        for (int q = 0; q < 8; ++q) wdst[tid + q * 256] = wsrc[tid + q * 256];
        __syncthreads();
        for (int kk = 0; kk < 64; kk += 4) {
            float a[4][4];
            #pragma unroll
            for (int r = 0; r < 4; ++r) {
                float4 av = *(const float4*)&lds_in[(ty * 4 + r) * PADLD + p * 64 + kk];
                a[r][0] = av.x; a[r][1] = av.y; a[r][2] = av.z; a[r][3] = av.w;
            }
            #pragma unroll
            for (int kq = 0; kq < 4; ++kq) {
                float4 wv = *(const float4*)&lds_w[(kk + kq) * EMBD + tx * 4];
                #pragma unroll
                for (int r = 0; r < 4; ++r) {
                    acc[r][0] += a[r][kq] * wv.x;
                    acc[r][1] += a[r][kq] * wv.y;
                    acc[r][2] += a[r][kq] * wv.z;
                    acc[r][3] += a[r][kq] * wv.w;
                }
            }
        }
    }
}

// ---------------- op embedding MLP: t = lrelu(sum of 5 table rows + b1); out = t@W2 + b2 ----
__global__ __launch_bounds__(256) void opemb_kernel(
    const int* __restrict__ ops, const int* __restrict__ params,
    const float* __restrict__ A, const float* __restrict__ b1,
    const float* __restrict__ W2, const float* __restrict__ b2,
    float* __restrict__ S0, float* __restrict__ S2)
{
    __shared__ float lds_w[64 * EMBD];
    __shared__ float lds_in[32 * PADLD];
    int tid = threadIdx.x;
    int node0 = blockIdx.x * 32;
    for (int q = tid; q < 1024; q += 256) {
        int r = q >> 5, c4 = q & 31;
        int node = node0 + r;
        int op = ops[node];
        float4 v = ((const float4*)(A + (size_t)op * EMBD))[c4];
        #pragma unroll
        for (int p = 0; p < 4; ++p) {
            int pv = params[node * 4 + p];
            float4 u = ((const float4*)(A + (size_t)((p + 1) * 64 + pv) * EMBD))[c4];
            v.x += u.x; v.y += u.y; v.z += u.z; v.w += u.w;
        }
        float4 bb = ((const float4*)b1)[c4];
        v.x = lrelu(v.x + bb.x); v.y = lrelu(v.y + bb.y);
        v.z = lrelu(v.z + bb.z); v.w = lrelu(v.w + bb.w);
        *(float4*)&lds_in[r * PADLD + c4 * 4] = v;
    }
    float acc[4][4] = {};
    gemm_core_128(lds_w, lds_in, W2, acc, tid);
    int ty = tid >> 5, tx = tid & 31;
    float4 bb = ((const float4*)b2)[tx];
    #pragma unroll
    for (int r = 0; r < 4; ++r) {
        float4 o;
        o.x = acc[r][0] + bb.x; o.y = acc[r][1] + bb.y;
        o.z = acc[r][2] + bb.z; o.w = acc[r][3] + bb.w;
        size_t idx = (size_t)(node0 + ty * 4 + r) * 32 + tx;
        ((float4*)S0)[idx] = o;
        ((float4*)S2)[idx] = o;
    }
}

// ---------------- GIN layer GEMM: out = lrelu(msg @ W + b), optional column-sum ----------
template <bool COLSUM>
__global__ __launch_bounds__(256) void gin_gemm_kernel(
    const float* __restrict__ in, const float* __restrict__ W,
    const float* __restrict__ bias, float* __restrict__ out,
    float* __restrict__ colsum)
{
    __shared__ float lds_w[64 * EMBD];
    __shared__ float lds_in[32 * PADLD];
    int tid = threadIdx.x;
    int node0 = blockIdx.x * 32;
    stage_rows(in, lds_in, node0, tid);
    float acc[4][4] = {};
    gemm_core_128(lds_w, lds_in, W, acc, tid);
    int ty = tid >> 5, tx = tid & 31;
    float4 bb = ((const float4*)bias)[tx];
    float cs[4] = {0.f, 0.f, 0.f, 0.f};
    #pragma unroll
    for (int r = 0; r < 4; ++r) {
        float4 o;
        o.x = lrelu(acc[r][0] + bb.x);
        o.y = lrelu(acc[r][1] + bb.y);
        o.z = lrelu(acc[r][2] + bb.z);
        o.w = lrelu(acc[r][3] + bb.w);
        ((float4*)out)[(size_t)(node0 + ty * 4 + r) * 32 + tx] = o;
        if (COLSUM) { cs[0] += o.x; cs[1] += o.y; cs[2] += o.z; cs[3] += o.w; }
    }
    if (COLSUM) {
        __syncthreads();                 // done reading lds_in
        float* red = lds_in;
        #pragma unroll
        for (int c = 0; c < 4; ++c) red[ty * EMBD + tx * 4 + c] = cs[c];
        __syncthreads();
        if (ty == 0) {
            #pragma unroll
            for (int c = 0; c < 4; ++c) {
                float s = 0.f;
                #pragma unroll
                for (int q = 0; q < 8; ++q) s += red[q * EMBD + tx * 4 + c];
                atomicAdd(&colsum[tx * 4 + c], s);
            }
        }
    }
}

// ---------------- out2 = [Sf | Si] @ comb_w + comb_b ----------------
__global__ __launch_bounds__(256) void out2_kernel(
    const float* __restrict__ Sf, const float* __restrict__ Si,
    const float* __restrict__ CW, const float* __restrict__ cb,
    float* __restrict__ out)
{
    __shared__ float lds_w[64 * EMBD];
    __shared__ float lds_in[32 * PADLD];
    int tid = threadIdx.x;
    int node0 = blockIdx.x * 32;
    float acc[4][4] = {};
    stage_rows(Sf, lds_in, node0, tid);
    gemm_core_128(lds_w, lds_in, CW, acc, tid);
    __syncthreads();
    stage_rows(Si, lds_in, node0, tid);
    gemm_core_128(lds_w, lds_in, CW + EMBD * EMBD, acc, tid);
    int ty = tid >> 5, tx = tid & 31;
    float4 bb = ((const float4*)cb)[tx];
    #pragma unroll
    for (int r = 0; r < 4; ++r) {
        float4 o;
        o.x = acc[r][0] + bb.x; o.y = acc[r][1] + bb.y;
        o.z = acc[r][2] + bb.z; o.w = acc[r][3] + bb.w;
        ((float4*)out)[(size_t)(node0 + ty * 4 + r) * 32 + tx] = o;
    }
}

// ---------------- graph-level heads -> out1[128] ----------------
__global__ void final_kernel(const float* __restrict__ convsum,
    const float* __restrict__ mw1, const float* __restrict__ mb1,
    const float* __restrict__ mw2, const float* __restrict__ mb2,
    const float* __restrict__ iw1, const float* __restrict__ ib1,
    const float* __restrict__ iw2, const float* __restrict__ ib2,
    const float* __restrict__ cw, const float* __restrict__ cb,
    float* __restrict__ out1)
{
    __shared__ float x[384];
    __shared__ float t1[128];
    __shared__ float t2[128];
    __shared__ float g1[128];
    __shared__ float g2[128];
    int j = threadIdx.x;   // 128 threads
    x[j] = convsum[j]; x[128 + j] = convsum[128 + j]; x[256 + j] = convsum[256 + j];
    __syncthreads();
    float a = mb1[j];
    for (int k = 0; k < 384; ++k) a += x[k] * mw1[k * 128 + j];
    t1[j] = lrelu(a);
    float c = ib1[j];
    for (int k = 0; k < 384; ++k) c += x[256 + (k & 127)] * iw1[k * 128 + j];
    t2[j] = lrelu(c);
    __syncthreads();
    float b = mb2[j];
    float d = ib2[j];
    for (int k = 0; k < 128; ++k) {
        b += t1[k] * mw2[k * 128 + j];
        d += t2[k] * iw2[k * 128 + j];
    }
    g1[j] = b; g2[j] = d;
    __syncthreads();
    float e = cb[j];
    for (int k = 0; k < 128; ++k)
        e += g1[k] * cw[k * 128 + j] + g2[k] * cw[(128 + k) * 128 + j];
    out1[j] = e;
}

extern "C" void kernel_launch(void* const* d_in, const int* in_sizes, int n_in,
                              void* d_out, int out_size, void* d_ws, size_t ws_size,
                              hipStream_t stream)
{
    (void)n_in; (void)out_size; (void)ws_size;
    const int*   ops    = (const int*)d_in[0];
    const int*   params = (const int*)d_in[1];
    const int*   esrc   = (const int*)d_in[2];
    const int*   edst   = (const int*)d_in[3];
    const float* opT    = (const float*)d_in[4];
    const float* parT   = (const float*)d_in[5];
    const float* ow1    = (const float*)d_in[6];
    const float* ob1    = (const float*)d_in[7];
    const float* ow2    = (const float*)d_in[8];
    const float* ob2    = (const float*)d_in[9];
    const float* convw  = (const float*)d_in[10];
    const float* convb  = (const float*)d_in[11];
    const float* mw1    = (const float*)d_in[12];
    const float* mb1    = (const float*)d_in[13];
    const float* mw2    = (const float*)d_in[14];
    const float* mb2    = (const float*)d_in[15];
    const float* iw1    = (const float*)d_in[16];
    const float* ib1    = (const float*)d_in[17];
    const float* iw2    = (const float*)d_in[18];
    const float* ib2    = (const float*)d_in[19];
    const float* cw     = (const float*)d_in[20];
    const float* cb     = (const float*)d_in[21];

    const int N = in_sizes[0];      // 100000 (multiple of 32)
    const int E = in_sizes[2];      // 1600000

    // workspace layout (fp32 / int32), total ~169 MB
    float* S0      = (float*)d_ws;
    float* S1      = S0 + (size_t)N * EMBD;
    float* S2      = S1 + (size_t)N * EMBD;
    float* Atab    = S2 + (size_t)N * EMBD;           // 5*64*128
    float* convsum = Atab + 5 * 64 * EMBD;            // 384 used, 512 reserved
    int*   csr_f   = (int*)(convsum + 512);           // E
    int*   csr_i   = csr_f + E;                       // E
    int*   cnt_f   = csr_i + E;                       // N
    int*   cnt_i   = cnt_f + N;
    int*   cur_f   = cnt_i + N;
    int*   cur_i   = cur_f + N;
    int*   off_f   = cur_i + N;
    int*   off_i   = off_f + N;

    float* out1 = (float*)d_out;
    float* out2 = out1 + EMBD;          // [N][128]
    float* MSG  = out2;                 // scratch until final out2 write

    hipMemsetAsync(cnt_f, 0, sizeof(int) * (size_t)4 * N, stream);   // cnt_f,cnt_i,cur_f,cur_i
    hipMemsetAsync(convsum, 0, sizeof(float) * 512, stream);

    tables_kernel<<<320, 128, 0, stream>>>(opT, parT, ow1, Atab);
    count_kernel<<<(E + 255) / 256, 256, 0, stream>>>(esrc, edst, cnt_f, cnt_i, E);
    scan_kernel<<<2, 1024, 0, stream>>>(cnt_f, off_f, cnt_i, off_i, N);
    fill_kernel<<<(E + 255) / 256, 256, 0, stream>>>(esrc, edst, off_f, off_i,
                                                     cur_f, cur_i, csr_f, csr_i, E);
    opemb_kernel<<<N / 32, 256, 0, stream>>>(ops, params, Atab, ob1, ow2, ob2, S0, S2);

    const int aggGrid = (N + 3) / 4;
    // forward: S0 -> S1 -> S0 -> S1  (colsums per layer)
    agg_kernel<<<aggGrid, 256, 0, stream>>>(S0, csr_f, off_f, cnt_f, MSG, N);
    gin_gemm_kernel<true><<<N / 32, 256, 0, stream>>>(MSG, convw, convb, S1, convsum);
    agg_kernel<<<aggGrid, 256, 0, stream>>>(S1, csr_f, off_f, cnt_f, MSG, N);
    gin_gemm_kernel<true><<<N / 32, 256, 0, stream>>>(MSG, convw + 16384, convb + 128, S0, convsum + 128);
    agg_kernel<<<aggGrid, 256, 0, stream>>>(S0, csr_f, off_f, cnt_f, MSG, N);
    gin_gemm_kernel<true><<<N / 32, 256, 0, stream>>>(MSG, convw + 32768, convb + 256, S1, convsum + 256);
    // inverse: S2 -> S0 -> S2 -> S0  (no colsums)
    agg_kernel<<<aggGrid, 256, 0, stream>>>(S2, csr_i, off_i, cnt_i, MSG, N);
    gin_gemm_kernel<false><<<N / 32, 256, 0, stream>>>(MSG, convw, convb, S0, nullptr);
    agg_kernel<<<aggGrid, 256, 0, stream>>>(S0, csr_i, off_i, cnt_i, MSG, N);
    gin_gemm_kernel<false><<<N / 32, 256, 0, stream>>>(MSG, convw + 16384, convb + 128, S2, nullptr);
    agg_kernel<<<aggGrid, 256, 0, stream>>>(S2, csr_i, off_i, cnt_i, MSG, N);
    gin_gemm_kernel<false><<<N / 32, 256, 0, stream>>>(MSG, convw + 32768, convb + 256, S0, nullptr);

    final_kernel<<<1, 128, 0, stream>>>(convsum, mw1, mb1, mw2, mb2,
                                        iw1, ib1, iw2, ib2, cw, cb, out1);
    out2_kernel<<<N / 32, 256, 0, stream>>>(S1, S0, cw, cb, out2);
}

// Round 2
// 1447.193 us; speedup vs baseline: 1.6707x; 1.6707x over previous
//
#include <hip/hip_runtime.h>

// SemaEmb GIN network — round 2: fused agg+GEMM with bf16 MFMA.
// N=100000, E=1600000, EMB=128, L=3, P=4.

typedef unsigned int  uint;
typedef unsigned short ushort;
typedef float  f32x4  __attribute__((ext_vector_type(4)));
typedef short  bf16x8 __attribute__((ext_vector_type(8)));

__device__ __forceinline__ float lrelu(float x) { return x > 0.0f ? x : 0.01f * x; }
__device__ __forceinline__ ushort f2b(float x) {
    uint u = __float_as_uint(x);
    return (ushort)((u + 0x7fffu + ((u >> 16) & 1u)) >> 16);
}
__device__ __forceinline__ float lof(uint u) { return __uint_as_float(u << 16); }
__device__ __forceinline__ float hif(uint u) { return __uint_as_float(u & 0xffff0000u); }

// ---------------- fp32 folded tables: A[t*64+v][j] = emb_t[v] @ W1 block t ----------------
__global__ void tables_kernel(const float* __restrict__ opT, const float* __restrict__ parT,
                              const float* __restrict__ W1, float* __restrict__ A)
{
    int b = blockIdx.x;            // 0..319 : t*64+v
    int t = b >> 6, v = b & 63, j = threadIdx.x;
    const float* emb = (t == 0 ? opT : parT) + v * 128;
    const float* w = W1 + (size_t)t * 128 * 128;
    float acc = 0.f;
    for (int k = 0; k < 128; ++k) acc += emb[k] * w[k * 128 + j];
    A[(size_t)b * 128 + j] = acc;
}

// ---------------- bf16 transposed + pre-swizzled weight images ----------------
// For weight W[k][c] (out = in @ W): image byte layout
//   c*256 + ((k>>3)^(c&7))*16 + (k&7)*2   (row = output col c, 16B chunks XOR-swizzled)
__global__ void prep_w(const float* __restrict__ convw, const float* __restrict__ ow2,
                       const float* __restrict__ cw, ushort* __restrict__ Wt)
{
    int t = blockIdx.x * 256 + threadIdx.x;     // 6 images * 16384
    int img = t >> 14, idx = t & 16383;
    int k = idx >> 7, c = idx & 127;
    const float* src;
    if (img < 3)      src = convw + img * 16384;
    else if (img == 3) src = ow2;
    else              src = cw + (img - 4) * 16384;
    float v = src[k * 128 + c];
    int byteoff = (img << 15) + (c << 8) + ((((k >> 3) ^ (c & 7)) << 4)) + ((k & 7) << 1);
    Wt[byteoff >> 1] = f2b(v);
}

// ---------------- CSR build ----------------
__global__ void count_kernel(const int* __restrict__ src, const int* __restrict__ dst,
                             int* __restrict__ cnt_f, int* __restrict__ cnt_i, int e)
{
    int t = blockIdx.x * 256 + threadIdx.x;
    if (t >= e) return;
    atomicAdd(&cnt_f[dst[t]], 1);
    atomicAdd(&cnt_i[src[t]], 1);
}

__global__ void scan_kernel(const int* __restrict__ c0, int* __restrict__ o0,
                            const int* __restrict__ c1, int* __restrict__ o1, int n)
{
    const int* cnt = blockIdx.x ? c1 : c0;
    int* offs = blockIdx.x ? o1 : o0;
    __shared__ int wtot[16];
    __shared__ int carry;
    int tid = threadIdx.x;
    int lane = tid & 63, wv = tid >> 6;
    if (tid == 0) carry = 0;
    __syncthreads();
    for (int base = 0; base < n; base += 1024) {
        int i = base + tid;
        int v = (i < n) ? cnt[i] : 0;
        int incl = v;
        #pragma unroll
        for (int s = 1; s < 64; s <<= 1) {
            int t = __shfl_up(incl, s, 64);
            if (lane >= s) incl += t;
        }
        if (lane == 63) wtot[wv] = incl;
        __syncthreads();
        if (tid == 0) {
            int run = 0;
            #pragma unroll
            for (int q = 0; q < 16; ++q) { int t = wtot[q]; wtot[q] = run; run += t; }
        }
        __syncthreads();
        if (i < n) offs[i] = carry + wtot[wv] + incl - v;
        __syncthreads();
        if (tid == 1023) carry += wtot[15] + incl;
        __syncthreads();
    }
}

__global__ void fill_kernel(const int* __restrict__ src, const int* __restrict__ dst,
                            const int* __restrict__ off_f, const int* __restrict__ off_i,
                            int* __restrict__ cur_f, int* __restrict__ cur_i,
                            int* __restrict__ csr_f, int* __restrict__ csr_i, int e)
{
    int t = blockIdx.x * 256 + threadIdx.x;
    if (t >= e) return;
    int s = src[t], d = dst[t];
    int p = atomicAdd(&cur_f[d], 1);
    csr_f[off_f[d] + p] = s;
    int q = atomicAdd(&cur_i[s], 1);
    csr_i[off_i[s] + q] = d;
}

// ---------------- shared MFMA helpers ----------------
// A-tile/W-tile LDS layout: row r (256B) ; 16B chunk ch stored at ch^(r&7).
__device__ __forceinline__ void stage_w(const ushort* __restrict__ img, ushort* ldsW, int tid)
{
    const uint4* s = (const uint4*)img;
    uint4* d = (uint4*)ldsW;
    #pragma unroll
    for (int i = 0; i < 4; ++i) d[tid + (i << 9)] = s[tid + (i << 9)];
}

__device__ __forceinline__ void mfma_gemm_128(const ushort* ldsA, const ushort* ldsW,
                                              int lane, int row0, f32x4 acc[8])
{
    int l15 = lane & 15, lg = lane >> 4;
    int arow = row0 + l15;
    const char* Ab = (const char*)ldsA + arow * 256;
    int akey = (arow & 7) << 4;
    #pragma unroll
    for (int kk = 0; kk < 4; ++kk) {
        bf16x8 af = *(const bf16x8*)(Ab + ((((kk << 2) + lg) << 4) ^ akey));
        #pragma unroll
        for (int ct = 0; ct < 8; ++ct) {
            int c = (ct << 4) + l15;
            const char* Bb = (const char*)ldsW + c * 256;
            bf16x8 bf = *(const bf16x8*)(Bb + ((((kk << 2) + lg) << 4) ^ ((c & 7) << 4)));
            acc[ct] = __builtin_amdgcn_mfma_f32_16x16x32_bf16(af, bf, acc[ct], 0, 0, 0);
        }
    }
}

// ---------------- fused GIN layer: agg (CSR mean) + lrelu((feat+agg)@W + b) ----------------
template <bool COLSUM>
__global__ __launch_bounds__(512, 4) void gin_fused(
    const ushort* __restrict__ Sin, ushort* __restrict__ Sout,
    const ushort* __restrict__ Wimg, const float* __restrict__ bias,
    const int* __restrict__ csr, const int* __restrict__ offs, const int* __restrict__ cnt,
    float* __restrict__ colsum, int N)
{
    __shared__ __align__(16) ushort ldsW[16384];
    __shared__ __align__(16) ushort ldsA[16384];
    __shared__ float ldsCS[128];
    int tid = threadIdx.x, lane = tid & 63, w = tid >> 6;
    int node0 = blockIdx.x << 7;

    stage_w(Wimg, ldsW, tid);
    if (COLSUM && tid < 128) ldsCS[tid] = 0.f;

    // aggregation: wave w -> rows [w*16, w*16+16)
    const uint* Sp = (const uint*)Sin;
    for (int r = w << 4; r < (w << 4) + 16; ++r) {
        int g = node0 + r;
        float ax = 0.f, ay = 0.f;
        if (g < N) {
            int off = offs[g], deg = cnt[g];
            int d = 0;
            for (; d + 4 <= deg; d += 4) {
                int n0 = csr[off + d + 0], n1 = csr[off + d + 1];
                int n2 = csr[off + d + 2], n3 = csr[off + d + 3];
                uint v0 = Sp[(size_t)n0 * 64 + lane];
                uint v1 = Sp[(size_t)n1 * 64 + lane];
                uint v2 = Sp[(size_t)n2 * 64 + lane];
                uint v3 = Sp[(size_t)n3 * 64 + lane];
                ax += (lof(v0) + lof(v1)) + (lof(v2) + lof(v3));
                ay += (hif(v0) + hif(v1)) + (hif(v2) + hif(v3));
            }
            for (; d < deg; ++d) {
                uint v = Sp[(size_t)csr[off + d] * 64 + lane];
                ax += lof(v); ay += hif(v);
            }
            float invd = 1.0f / fmaxf((float)deg, 1.0f);
            uint self = Sp[(size_t)g * 64 + lane];
            ax = lof(self) + ax * invd;
            ay = hif(self) + ay * invd;
        }
        uint pk = (uint)f2b(ax) | ((uint)f2b(ay) << 16);
        *(uint*)((char*)ldsA + r * 256 + ((((lane >> 2) ^ (r & 7)) << 4)) + ((lane & 3) << 2)) = pk;
    }
    __syncthreads();

    f32x4 acc[8];
    #pragma unroll
    for (int i = 0; i < 8; ++i) acc[i] = f32x4{0.f, 0.f, 0.f, 0.f};
    mfma_gemm_128(ldsA, ldsW, lane, w << 4, acc);

    int l15 = lane & 15, lg = lane >> 4;
    #pragma unroll
    for (int ct = 0; ct < 8; ++ct) {
        int c = (ct << 4) + l15;
        float bb = bias[c];
        float csum = 0.f;
        #pragma unroll
        for (int j = 0; j < 4; ++j) {
            int g = node0 + (w << 4) + (lg << 2) + j;
            float o = lrelu(acc[ct][j] + bb);
            if (g < N) {
                Sout[(size_t)g * 128 + c] = f2b(o);
                csum += o;
            }
        }
        if (COLSUM) {
            csum += __shfl_xor(csum, 16);
            csum += __shfl_xor(csum, 32);
            if (lg == 0) atomicAdd(&ldsCS[c], csum);
        }
    }
    if (COLSUM) {
        __syncthreads();
        if (tid < 128) atomicAdd(&colsum[tid], ldsCS[tid]);
    }
}

// ---------------- op embedding MLP (tables -> lrelu -> @W2+b2), bf16 out x2 ----------------
__global__ __launch_bounds__(512, 4) void opemb_fused(
    const int* __restrict__ ops, const int* __restrict__ params,
    const float* __restrict__ Atab, const float* __restrict__ b1,
    const ushort* __restrict__ W2img, const float* __restrict__ b2,
    ushort* __restrict__ S0, ushort* __restrict__ S2, int N)
{
    __shared__ __align__(16) ushort ldsW[16384];
    __shared__ __align__(16) ushort ldsA[16384];
    int tid = threadIdx.x, lane = tid & 63, w = tid >> 6;
    int node0 = blockIdx.x << 7;

    stage_w(W2img, ldsW, tid);

    int r = tid >> 2, sub = tid & 3;      // 4 threads/row, 32 cols each
    int g = node0 + r;
    float4 acc4[8];
    if (g < N) {
        int op = ops[g];
        const float4* T = (const float4*)(Atab + ((size_t)op << 7) + (sub << 5));
        #pragma unroll
        for (int q = 0; q < 8; ++q) acc4[q] = T[q];
        #pragma unroll
        for (int p = 0; p < 4; ++p) {
            int pv = params[(g << 2) + p];
            const float4* Tp = (const float4*)(Atab + ((size_t)((p + 1) * 64 + pv) << 7) + (sub << 5));
            #pragma unroll
            for (int q = 0; q < 8; ++q) {
                float4 u = Tp[q];
                acc4[q].x += u.x; acc4[q].y += u.y; acc4[q].z += u.z; acc4[q].w += u.w;
            }
        }
        const float4* Bv = (const float4*)(b1 + (sub << 5));
        #pragma unroll
        for (int q = 0; q < 8; ++q) {
            float4 bb = Bv[q];
            acc4[q].x = lrelu(acc4[q].x + bb.x);
            acc4[q].y = lrelu(acc4[q].y + bb.y);
            acc4[q].z = lrelu(acc4[q].z + bb.z);
            acc4[q].w = lrelu(acc4[q].w + bb.w);
        }
    } else {
        #pragma unroll
        for (int q = 0; q < 8; ++q) acc4[q] = make_float4(0.f, 0.f, 0.f, 0.f);
    }
    int akey = r & 7;
    #pragma unroll
    for (int q2 = 0; q2 < 4; ++q2) {
        int ch = (sub << 2) + q2;
        float4 a = acc4[q2 * 2], b = acc4[q2 * 2 + 1];
        uint4 pk;
        pk.x = (uint)f2b(a.x) | ((uint)f2b(a.y) << 16);
        pk.y = (uint)f2b(a.z) | ((uint)f2b(a.w) << 16);
        pk.z = (uint)f2b(b.x) | ((uint)f2b(b.y) << 16);
        pk.w = (uint)f2b(b.z) | ((uint)f2b(b.w) << 16);
        *(uint4*)((char*)ldsA + r * 256 + ((ch ^ akey) << 4)) = pk;
    }
    __syncthreads();

    f32x4 acc[8];
    #pragma unroll
    for (int i = 0; i < 8; ++i) acc[i] = f32x4{0.f, 0.f, 0.f, 0.f};
    mfma_gemm_128(ldsA, ldsW, lane, w << 4, acc);

    int l15 = lane & 15, lg = lane >> 4;
    #pragma unroll
    for (int ct = 0; ct < 8; ++ct) {
        int c = (ct << 4) + l15;
        float bb = b2[c];
        #pragma unroll
        for (int j = 0; j < 4; ++j) {
            int gg = node0 + (w << 4) + (lg << 2) + j;
            if (gg < N) {
                ushort ob = f2b(acc[ct][j] + bb);     // no lrelu on layer 2
                S0[(size_t)gg * 128 + c] = ob;
                S2[(size_t)gg * 128 + c] = ob;
            }
        }
    }
}

// ---------------- out2 = [Sf | Si] @ comb_w + comb_b (fp32 out) ----------------
__device__ __forceinline__ void stage_a_bf16(const ushort* __restrict__ S, ushort* ldsA,
                                             int node0, int tid, int N)
{
    #pragma unroll
    for (int i = 0; i < 4; ++i) {
        int chunk = tid + (i << 9);          // 0..2047
        int r = chunk >> 4, cin = chunk & 15;
        int g = node0 + r;
        uint4 v;
        if (g < N) v = *(const uint4*)(S + (size_t)g * 128 + (cin << 3));
        else       { v.x = 0; v.y = 0; v.z = 0; v.w = 0; }
        *(uint4*)((char*)ldsA + r * 256 + ((cin ^ (r & 7)) << 4)) = v;
    }
}

__global__ __launch_bounds__(512, 4) void out2_fused(
    const ushort* __restrict__ Sf, const ushort* __restrict__ Si,
    const ushort* __restrict__ CWimg, const float* __restrict__ cb,
    float* __restrict__ out, int N)
{
    __shared__ __align__(16) ushort ldsW[16384];
    __shared__ __align__(16) ushort ldsA[16384];
    int tid = threadIdx.x, lane = tid & 63, w = tid >> 6;
    int node0 = blockIdx.x << 7;
    f32x4 acc[8];
    #pragma unroll
    for (int i = 0; i < 8; ++i) acc[i] = f32x4{0.f, 0.f, 0.f, 0.f};
    #pragma unroll
    for (int pass = 0; pass < 2; ++pass) {
        if (pass) __syncthreads();
        stage_w(CWimg + (pass << 14), ldsW, tid);
        stage_a_bf16(pass ? Si : Sf, ldsA, node0, tid, N);
        __syncthreads();
        mfma_gemm_128(ldsA, ldsW, lane, w << 4, acc);
    }
    int l15 = lane & 15, lg = lane >> 4;
    #pragma unroll
    for (int ct = 0; ct < 8; ++ct) {
        int c = (ct << 4) + l15;
        float bb = cb[c];
        #pragma unroll
        for (int j = 0; j < 4; ++j) {
            int g = node0 + (w << 4) + (lg << 2) + j;
            if (g < N) out[(size_t)g * 128 + c] = acc[ct][j] + bb;
        }
    }
}

// ---------------- graph-level heads -> out1[128] ----------------
__global__ void final_kernel(const float* __restrict__ convsum,
    const float* __restrict__ mw1, const float* __restrict__ mb1,
    const float* __restrict__ mw2, const float* __restrict__ mb2,
    const float* __restrict__ iw1, const float* __restrict__ ib1,
    const float* __restrict__ iw2, const float* __restrict__ ib2,
    const float* __restrict__ cw, const float* __restrict__ cb,
    float* __restrict__ out1)
{
    __shared__ float x[384];
    __shared__ float t1[128];
    __shared__ float t2[128];
    __shared__ float g1[128];
    __shared__ float g2[128];
    int j = threadIdx.x;   // 128 threads
    x[j] = convsum[j]; x[128 + j] = convsum[128 + j]; x[256 + j] = convsum[256 + j];
    __syncthreads();
    float a = mb1[j];
    for (int k = 0; k < 384; ++k) a += x[k] * mw1[k * 128 + j];
    t1[j] = lrelu(a);
    float c = ib1[j];
    for (int k = 0; k < 384; ++k) c += x[256 + (k & 127)] * iw1[k * 128 + j];
    t2[j] = lrelu(c);
    __syncthreads();
    float b = mb2[j];
    float d = ib2[j];
    for (int k = 0; k < 128; ++k) {
        b += t1[k] * mw2[k * 128 + j];
        d += t2[k] * iw2[k * 128 + j];
    }
    g1[j] = b; g2[j] = d;
    __syncthreads();
    float e = cb[j];
    for (int k = 0; k < 128; ++k)
        e += g1[k] * cw[k * 128 + j] + g2[k] * cw[(128 + k) * 128 + j];
    out1[j] = e;
}

extern "C" void kernel_launch(void* const* d_in, const int* in_sizes, int n_in,
                              void* d_out, int out_size, void* d_ws, size_t ws_size,
                              hipStream_t stream)
{
    (void)n_in; (void)out_size; (void)ws_size;
    const int*   ops    = (const int*)d_in[0];
    const int*   params = (const int*)d_in[1];
    const int*   esrc   = (const int*)d_in[2];
    const int*   edst   = (const int*)d_in[3];
    const float* opT    = (const float*)d_in[4];
    const float* parT   = (const float*)d_in[5];
    const float* ow1    = (const float*)d_in[6];
    const float* ob1    = (const float*)d_in[7];
    const float* ow2    = (const float*)d_in[8];
    const float* ob2    = (const float*)d_in[9];
    const float* convw  = (const float*)d_in[10];
    const float* convb  = (const float*)d_in[11];
    const float* mw1    = (const float*)d_in[12];
    const float* mb1    = (const float*)d_in[13];
    const float* mw2    = (const float*)d_in[14];
    const float* mb2    = (const float*)d_in[15];
    const float* iw1    = (const float*)d_in[16];
    const float* ib1    = (const float*)d_in[17];
    const float* iw2    = (const float*)d_in[18];
    const float* ib2    = (const float*)d_in[19];
    const float* cw     = (const float*)d_in[20];
    const float* cb     = (const float*)d_in[21];

    const int N = in_sizes[0];      // 100000
    const int E = in_sizes[2];      // 1600000

    // workspace layout
    ushort* S0   = (ushort*)d_ws;                    // [N][128] bf16
    ushort* S1   = S0 + (size_t)N * 128;
    ushort* S2   = S1 + (size_t)N * 128;
    ushort* Wt   = S2 + (size_t)N * 128;             // 6 * 16384 bf16 images
    float*  Atab = (float*)(Wt + 6 * 16384);         // 320*128 fp32
    float*  convsum = Atab + 320 * 128;              // 384 used, 512 reserved
    int*    csr_f = (int*)(convsum + 512);           // E
    int*    csr_i = csr_f + E;                       // E
    int*    cnt_f = csr_i + E;                       // N
    int*    cnt_i = cnt_f + N;
    int*    cur_f = cnt_i + N;
    int*    cur_i = cur_f + N;
    int*    off_f = cur_i + N;
    int*    off_i = off_f + N;

    float* out1 = (float*)d_out;
    float* out2 = out1 + 128;

    hipMemsetAsync(cnt_f, 0, sizeof(int) * (size_t)4 * N, stream);
    hipMemsetAsync(convsum, 0, sizeof(float) * 512, stream);

    tables_kernel<<<320, 128, 0, stream>>>(opT, parT, ow1, Atab);
    prep_w<<<384, 256, 0, stream>>>(convw, ow2, cw, Wt);
    count_kernel<<<(E + 255) / 256, 256, 0, stream>>>(esrc, edst, cnt_f, cnt_i, E);
    scan_kernel<<<2, 1024, 0, stream>>>(cnt_f, off_f, cnt_i, off_i, N);
    fill_kernel<<<(E + 255) / 256, 256, 0, stream>>>(esrc, edst, off_f, off_i,
                                                     cur_f, cur_i, csr_f, csr_i, E);

    const int grid = (N + 127) / 128;
    opemb_fused<<<grid, 512, 0, stream>>>(ops, params, Atab, ob1, Wt + 3 * 16384, ob2, S0, S2, N);

    // forward: S0 -> S1 -> S0 -> S1  (colsums per layer)
    gin_fused<true><<<grid, 512, 0, stream>>>(S0, S1, Wt,             convb,       csr_f, off_f, cnt_f, convsum,       N);
    gin_fused<true><<<grid, 512, 0, stream>>>(S1, S0, Wt + 16384,     convb + 128, csr_f, off_f, cnt_f, convsum + 128, N);
    gin_fused<true><<<grid, 512, 0, stream>>>(S0, S1, Wt + 2 * 16384, convb + 256, csr_f, off_f, cnt_f, convsum + 256, N);
    // inverse: S2 -> S0 -> S2 -> S0
    gin_fused<false><<<grid, 512, 0, stream>>>(S2, S0, Wt,             convb,       csr_i, off_i, cnt_i, nullptr, N);
    gin_fused<false><<<grid, 512, 0, stream>>>(S0, S2, Wt + 16384,     convb + 128, csr_i, off_i, cnt_i, nullptr, N);
    gin_fused<false><<<grid, 512, 0, stream>>>(S2, S0, Wt + 2 * 16384, convb + 256, csr_i, off_i, cnt_i, nullptr, N);

    final_kernel<<<1, 128, 0, stream>>>(convsum, mw1, mb1, mw2, mb2,
                                        iw1, ib1, iw2, ib2, cw, cb, out1);
    out2_fused<<<grid, 512, 0, stream>>>(S1, S0, Wt + 4 * 16384, cb, out2, N);
}

// Round 3
// 930.610 us; speedup vs baseline: 2.5981x; 1.5551x over previous
//
#include <hip/hip_runtime.h>

// SemaEmb GIN network — round 3: binned CSR build + merged fwd/inv layers.
// N=100000, E=1600000, EMB=128, L=3, P=4.

typedef unsigned int  uint;
typedef unsigned short ushort;
typedef float  f32x4  __attribute__((ext_vector_type(4)));
typedef short  bf16x8 __attribute__((ext_vector_type(8)));

#define ABITS 9          // 512 nodes per bin
#define CAPB  12288      // entries per bin segment (expected ~8192, +45 sigma)
#define CHUNK 2048       // edges per binpass block

__device__ __forceinline__ float lrelu(float x) { return x > 0.0f ? x : 0.01f * x; }
__device__ __forceinline__ ushort f2b(float x) {
    uint u = __float_as_uint(x);
    return (ushort)((u + 0x7fffu + ((u >> 16) & 1u)) >> 16);
}
__device__ __forceinline__ float lof(uint u) { return __uint_as_float(u << 16); }
__device__ __forceinline__ float hif(uint u) { return __uint_as_float(u & 0xffff0000u); }

// ---------------- fp32 folded tables: A[t*64+v][j] = emb_t[v] @ W1 block t ----------------
__global__ void tables_kernel(const float* __restrict__ opT, const float* __restrict__ parT,
                              const float* __restrict__ W1, float* __restrict__ A)
{
    int b = blockIdx.x;            // 0..319 : t*64+v
    int t = b >> 6, v = b & 63, j = threadIdx.x;
    const float* emb = (t == 0 ? opT : parT) + v * 128;
    const float* w = W1 + (size_t)t * 128 * 128;
    float acc = 0.f;
    for (int k = 0; k < 128; ++k) acc += emb[k] * w[k * 128 + j];
    A[(size_t)b * 128 + j] = acc;
}

// ---------------- bf16 transposed + pre-swizzled weight images ----------------
__global__ void prep_w(const float* __restrict__ convw, const float* __restrict__ ow2,
                       const float* __restrict__ cw, ushort* __restrict__ Wt)
{
    int t = blockIdx.x * 256 + threadIdx.x;     // 6 images * 16384
    int img = t >> 14, idx = t & 16383;
    int k = idx >> 7, c = idx & 127;
    const float* src;
    if (img < 3)      src = convw + img * 16384;
    else if (img == 3) src = ow2;
    else              src = cw + (img - 4) * 16384;
    float v = src[k * 128 + c];
    int byteoff = (img << 15) + (c << 8) + ((((k >> 3) ^ (c & 7)) << 4)) + ((k & 7) << 1);
    Wt[byteoff >> 1] = f2b(v);
}

// ---------------- CSR build pass A: bin edges by key>>ABITS (both directions) ----------------
// Entry: (key, payload). fwd: key=dst,pay=src (bins [0,nb)); inv: key=src,pay=dst (bins [nb,2nb)).
__global__ __launch_bounds__(256) void binpass_kernel(
    const int* __restrict__ esrc, const int* __restrict__ edst, int E, int nb,
    int* __restrict__ gcur, uint2* __restrict__ binbuf)
{
    __shared__ int hist[448];
    __shared__ int lstart[448];
    __shared__ int gbase[448];
    __shared__ int lcur[448];
    __shared__ int gsum[8];
    __shared__ uint sKey[CHUNK * 2];
    __shared__ uint sPay[CHUNK * 2];
    __shared__ ushort sBin[CHUNK * 2];
    int tid = threadIdx.x, lane = tid & 63;
    int nb2 = nb * 2;

    for (int chunk = blockIdx.x; (size_t)chunk * CHUNK < (size_t)E; chunk += gridDim.x) {
        int base = chunk * CHUNK;
        int cnt = min(CHUNK, E - base);
        for (int i = tid; i < 448; i += 256) hist[i] = 0;
        __syncthreads();
        int s[8], d[8];
        #pragma unroll
        for (int i = 0; i < 8; ++i) {
            int idx = i * 256 + tid;
            if (idx < cnt) {
                s[i] = esrc[base + idx];
                d[i] = edst[base + idx];
                atomicAdd(&hist[d[i] >> ABITS], 1);
                atomicAdd(&hist[nb + (s[i] >> ABITS)], 1);
            } else s[i] = -1;
        }
        __syncthreads();
        // exclusive scan hist[0..447] -> lstart
        #pragma unroll
        for (int k = 0; k < 2; ++k) {
            int idx = k * 256 + tid;
            int v = (idx < 448) ? hist[idx] : 0;
            int p = v;
            #pragma unroll
            for (int sh = 1; sh < 64; sh <<= 1) { int t = __shfl_up(p, sh, 64); if (lane >= sh) p += t; }
            if (idx < 448) {
                lstart[idx] = p - v;
                if (lane == 63) gsum[idx >> 6] = p;
            }
        }
        __syncthreads();
        if (tid == 0) { int run = 0; for (int g = 0; g < 7; ++g) { int t = gsum[g]; gsum[g] = run; run += t; } }
        __syncthreads();
        #pragma unroll
        for (int k = 0; k < 2; ++k) {
            int idx = k * 256 + tid;
            if (idx < 448) lstart[idx] += gsum[idx >> 6];
        }
        __syncthreads();
        // reserve global space per bin, init cursors
        for (int i = tid; i < nb2; i += 256) {
            int h = hist[i];
            gbase[i] = h ? atomicAdd(&gcur[i], h) : 0;
            lcur[i] = lstart[i];
        }
        __syncthreads();
        // scatter entries into LDS staging (grouped by bin)
        #pragma unroll
        for (int i = 0; i < 8; ++i) {
            if (s[i] >= 0) {
                int bf = d[i] >> ABITS;
                int p = atomicAdd(&lcur[bf], 1);
                sKey[p] = (uint)d[i]; sPay[p] = (uint)s[i]; sBin[p] = (ushort)bf;
                int bi = nb + (s[i] >> ABITS);
                int q = atomicAdd(&lcur[bi], 1);
                sKey[q] = (uint)s[i]; sPay[q] = (uint)d[i]; sBin[q] = (ushort)bi;
            }
        }
        __syncthreads();
        // coalesced copy-out (runs grouped by bin)
        int total = 2 * cnt;
        for (int p = tid; p < total; p += 256) {
            int b = sBin[p];
            int pos = gbase[b] + (p - lstart[b]);
            if (pos < CAPB) binbuf[(size_t)b * CAPB + pos] = make_uint2(sKey[p], sPay[p]);
        }
        __syncthreads();
    }
}

// ---------------- CSR build pass B: per-bin CSR + off/cnt (no global scan needed) ----------
__global__ __launch_bounds__(256) void csrpass_kernel(
    const uint2* __restrict__ binbuf, const int* __restrict__ gcur, int nb, int N,
    int* __restrict__ csr_f, int* __restrict__ off_f, int* __restrict__ cnt_f,
    int* __restrict__ csr_i, int* __restrict__ off_i, int* __restrict__ cnt_i)
{
    __shared__ int hist[512];
    __shared__ int loff[512];
    __shared__ int cur[512];
    __shared__ int gsum[8];
    int b = blockIdx.x;
    int dir = (b >= nb) ? 1 : 0;
    int binLocal = dir ? b - nb : b;
    int node0 = binLocal << ABITS;
    int nn = min(512, N - node0);
    int tid = threadIdx.x, lane = tid & 63;
    int total = min(gcur[b], CAPB);
    const uint2* seg = binbuf + (size_t)b * CAPB;
    int* csr = dir ? csr_i : csr_f;
    int* off = dir ? off_i : off_f;
    int* cnt = dir ? cnt_i : cnt_f;

    for (int i = tid; i < 512; i += 256) hist[i] = 0;
    __syncthreads();
    for (int e = tid; e < total; e += 256) {
        uint2 kp = seg[e];
        atomicAdd(&hist[kp.x - (uint)node0], 1);
    }
    __syncthreads();
    // exclusive scan 512 -> loff
    #pragma unroll
    for (int k = 0; k < 2; ++k) {
        int idx = k * 256 + tid;
        int v = hist[idx];
        int p = v;
        #pragma unroll
        for (int sh = 1; sh < 64; sh <<= 1) { int t = __shfl_up(p, sh, 64); if (lane >= sh) p += t; }
        loff[idx] = p - v;
        if (lane == 63) gsum[idx >> 6] = p;
    }
    __syncthreads();
    if (tid == 0) { int run = 0; for (int g = 0; g < 8; ++g) { int t = gsum[g]; gsum[g] = run; run += t; } }
    __syncthreads();
    #pragma unroll
    for (int k = 0; k < 2; ++k) {
        int idx = k * 256 + tid;
        loff[idx] += gsum[idx >> 6];
    }
    __syncthreads();
    int csrBase = binLocal * CAPB;
    for (int i = tid; i < 512; i += 256) {
        cur[i] = loff[i];
        if (i < nn) { off[node0 + i] = csrBase + loff[i]; cnt[node0 + i] = hist[i]; }
    }
    __syncthreads();
    int* csrSeg = csr + csrBase;
    for (int e = tid; e < total; e += 256) {
        uint2 kp = seg[e];
        int p = atomicAdd(&cur[kp.x - (uint)node0], 1);
        csrSeg[p] = (int)kp.y;
    }
}

// ---------------- shared MFMA helpers ----------------
// A-tile/W-tile LDS layout: row r (256B); 16B chunk ch stored at ch^(r&7).
__device__ __forceinline__ void stage_w(const ushort* __restrict__ img, ushort* ldsW, int tid)
{
    const uint4* s = (const uint4*)img;
    uint4* d = (uint4*)ldsW;
    #pragma unroll
    for (int i = 0; i < 4; ++i) d[tid + (i << 9)] = s[tid + (i << 9)];
}

__device__ __forceinline__ void mfma_gemm_128(const ushort* ldsA, const ushort* ldsW,
                                              int lane, int row0, f32x4 acc[8])
{
    int l15 = lane & 15, lg = lane >> 4;
    int arow = row0 + l15;
    const char* Ab = (const char*)ldsA + arow * 256;
    int akey = (arow & 7) << 4;
    #pragma unroll
    for (int kk = 0; kk < 4; ++kk) {
        bf16x8 af = *(const bf16x8*)(Ab + ((((kk << 2) + lg) << 4) ^ akey));
        #pragma unroll
        for (int ct = 0; ct < 8; ++ct) {
            int c = (ct << 4) + l15;
            const char* Bb = (const char*)ldsW + c * 256;
            bf16x8 bf = *(const bf16x8*)(Bb + ((((kk << 2) + lg) << 4) ^ ((c & 7) << 4)));
            acc[ct] = __builtin_amdgcn_mfma_f32_16x16x32_bf16(af, bf, acc[ct], 0, 0, 0);
        }
    }
}

// ---------------- merged fwd+inv GIN layer: agg (CSR mean) + lrelu((feat+agg)@W + b) --------
__global__ __launch_bounds__(512, 4) void gin_fused2(
    const ushort* __restrict__ Sf_in, ushort* __restrict__ Sf_out,
    const ushort* __restrict__ Si_in, ushort* __restrict__ Si_out,
    const ushort* __restrict__ Wimg, const float* __restrict__ bias,
    const int* __restrict__ csr_f, const int* __restrict__ off_f, const int* __restrict__ cnt_f,
    const int* __restrict__ csr_i, const int* __restrict__ off_i, const int* __restrict__ cnt_i,
    float* __restrict__ colsum, int N)
{
    __shared__ __align__(16) ushort ldsW[16384];
    __shared__ __align__(16) ushort ldsA[16384];
    __shared__ float ldsCS[128];
    int tid = threadIdx.x, lane = tid & 63, w = tid >> 6;
    bool fwd = (blockIdx.x & 1) == 0;
    int node0 = (blockIdx.x >> 1) << 7;
    const ushort* Sin = fwd ? Sf_in : Si_in;
    ushort* Sout = fwd ? Sf_out : Si_out;
    const int* csr  = fwd ? csr_f : csr_i;
    const int* offs = fwd ? off_f : off_i;
    const int* cnt  = fwd ? cnt_f : cnt_i;

    stage_w(Wimg, ldsW, tid);
    if (fwd && tid < 128) ldsCS[tid] = 0.f;

    // aggregation: wave w -> rows [w*16, w*16+16)
    const uint* Sp = (const uint*)Sin;
    for (int r = w << 4; r < (w << 4) + 16; ++r) {
        int g = node0 + r;
        float ax = 0.f, ay = 0.f;
        if (g < N) {
            int off = offs[g], deg = cnt[g];
            int d = 0;
            for (; d + 8 <= deg; d += 8) {
                int n0 = csr[off + d + 0], n1 = csr[off + d + 1];
                int n2 = csr[off + d + 2], n3 = csr[off + d + 3];
                int n4 = csr[off + d + 4], n5 = csr[off + d + 5];
                int n6 = csr[off + d + 6], n7 = csr[off + d + 7];
                uint v0 = Sp[(size_t)n0 * 64 + lane];
                uint v1 = Sp[(size_t)n1 * 64 + lane];
                uint v2 = Sp[(size_t)n2 * 64 + lane];
                uint v3 = Sp[(size_t)n3 * 64 + lane];
                uint v4 = Sp[(size_t)n4 * 64 + lane];
                uint v5 = Sp[(size_t)n5 * 64 + lane];
                uint v6 = Sp[(size_t)n6 * 64 + lane];
                uint v7 = Sp[(size_t)n7 * 64 + lane];
                ax += ((lof(v0) + lof(v1)) + (lof(v2) + lof(v3)))
                    + ((lof(v4) + lof(v5)) + (lof(v6) + lof(v7)));
                ay += ((hif(v0) + hif(v1)) + (hif(v2) + hif(v3)))
                    + ((hif(v4) + hif(v5)) + (hif(v6) + hif(v7)));
            }
            if (d + 4 <= deg) {
                int n0 = csr[off + d + 0], n1 = csr[off + d + 1];
                int n2 = csr[off + d + 2], n3 = csr[off + d + 3];
                uint v0 = Sp[(size_t)n0 * 64 + lane];
                uint v1 = Sp[(size_t)n1 * 64 + lane];
                uint v2 = Sp[(size_t)n2 * 64 + lane];
                uint v3 = Sp[(size_t)n3 * 64 + lane];
                ax += (lof(v0) + lof(v1)) + (lof(v2) + lof(v3));
                ay += (hif(v0) + hif(v1)) + (hif(v2) + hif(v3));
                d += 4;
            }
            for (; d < deg; ++d) {
                uint v = Sp[(size_t)csr[off + d] * 64 + lane];
                ax += lof(v); ay += hif(v);
            }
            float invd = 1.0f / fmaxf((float)deg, 1.0f);
            uint self = Sp[(size_t)g * 64 + lane];
            ax = lof(self) + ax * invd;
            ay = hif(self) + ay * invd;
        }
        uint pk = (uint)f2b(ax) | ((uint)f2b(ay) << 16);
        *(uint*)((char*)ldsA + r * 256 + ((((lane >> 2) ^ (r & 7)) << 4)) + ((lane & 3) << 2)) = pk;
    }
    __syncthreads();

    f32x4 acc[8];
    #pragma unroll
    for (int i = 0; i < 8; ++i) acc[i] = f32x4{0.f, 0.f, 0.f, 0.f};
    mfma_gemm_128(ldsA, ldsW, lane, w << 4, acc);

    int l15 = lane & 15, lg = lane >> 4;
    #pragma unroll
    for (int ct = 0; ct < 8; ++ct) {
        int c = (ct << 4) + l15;
        float bb = bias[c];
        float csum = 0.f;
        #pragma unroll
        for (int j = 0; j < 4; ++j) {
            int g = node0 + (w << 4) + (lg << 2) + j;
            float o = lrelu(acc[ct][j] + bb);
            if (g < N) {
                Sout[(size_t)g * 128 + c] = f2b(o);
                csum += o;
            }
        }
        if (fwd) {
            csum += __shfl_xor(csum, 16);
            csum += __shfl_xor(csum, 32);
            if (lg == 0) atomicAdd(&ldsCS[c], csum);
        }
    }
    if (fwd) {
        __syncthreads();
        if (tid < 128) atomicAdd(&colsum[tid], ldsCS[tid]);
    }
}

// ---------------- op embedding MLP (tables -> lrelu -> @W2+b2), bf16 out x2 ----------------
__global__ __launch_bounds__(512, 4) void opemb_fused(
    const int* __restrict__ ops, const int* __restrict__ params,
    const float* __restrict__ Atab, const float* __restrict__ b1,
    const ushort* __restrict__ W2img, const float* __restrict__ b2,
    ushort* __restrict__ S0, ushort* __restrict__ S2, int N)
{
    __shared__ __align__(16) ushort ldsW[16384];
    __shared__ __align__(16) ushort ldsA[16384];
    int tid = threadIdx.x, lane = tid & 63, w = tid >> 6;
    int node0 = blockIdx.x << 7;

    stage_w(W2img, ldsW, tid);

    int r = tid >> 2, sub = tid & 3;      // 4 threads/row, 32 cols each
    int g = node0 + r;
    float4 acc4[8];
    if (g < N) {
        int op = ops[g];
        const float4* T = (const float4*)(Atab + ((size_t)op << 7) + (sub << 5));
        #pragma unroll
        for (int q = 0; q < 8; ++q) acc4[q] = T[q];
        #pragma unroll
        for (int p = 0; p < 4; ++p) {
            int pv = params[(g << 2) + p];
            const float4* Tp = (const float4*)(Atab + ((size_t)((p + 1) * 64 + pv) << 7) + (sub << 5));
            #pragma unroll
            for (int q = 0; q < 8; ++q) {
                float4 u = Tp[q];
                acc4[q].x += u.x; acc4[q].y += u.y; acc4[q].z += u.z; acc4[q].w += u.w;
            }
        }
        const float4* Bv = (const float4*)(b1 + (sub << 5));
        #pragma unroll
        for (int q = 0; q < 8; ++q) {
            float4 bb = Bv[q];
            acc4[q].x = lrelu(acc4[q].x + bb.x);
            acc4[q].y = lrelu(acc4[q].y + bb.y);
            acc4[q].z = lrelu(acc4[q].z + bb.z);
            acc4[q].w = lrelu(acc4[q].w + bb.w);
        }
    } else {
        #pragma unroll
        for (int q = 0; q < 8; ++q) acc4[q] = make_float4(0.f, 0.f, 0.f, 0.f);
    }
    int akey = r & 7;
    #pragma unroll
    for (int q2 = 0; q2 < 4; ++q2) {
        int ch = (sub << 2) + q2;
        float4 a = acc4[q2 * 2], b = acc4[q2 * 2 + 1];
        uint4 pk;
        pk.x = (uint)f2b(a.x) | ((uint)f2b(a.y) << 16);
        pk.y = (uint)f2b(a.z) | ((uint)f2b(a.w) << 16);
        pk.z = (uint)f2b(b.x) | ((uint)f2b(b.y) << 16);
        pk.w = (uint)f2b(b.z) | ((uint)f2b(b.w) << 16);
        *(uint4*)((char*)ldsA + r * 256 + ((ch ^ akey) << 4)) = pk;
    }
    __syncthreads();

    f32x4 acc[8];
    #pragma unroll
    for (int i = 0; i < 8; ++i) acc[i] = f32x4{0.f, 0.f, 0.f, 0.f};
    mfma_gemm_128(ldsA, ldsW, lane, w << 4, acc);

    int l15 = lane & 15, lg = lane >> 4;
    #pragma unroll
    for (int ct = 0; ct < 8; ++ct) {
        int c = (ct << 4) + l15;
        float bb = b2[c];
        #pragma unroll
        for (int j = 0; j < 4; ++j) {
            int gg = node0 + (w << 4) + (lg << 2) + j;
            if (gg < N) {
                ushort ob = f2b(acc[ct][j] + bb);     // no lrelu on layer 2
                S0[(size_t)gg * 128 + c] = ob;
                S2[(size_t)gg * 128 + c] = ob;
            }
        }
    }
}

// ---------------- out2 = [Sf | Si] @ comb_w + comb_b (fp32 out) ----------------
__device__ __forceinline__ void stage_a_bf16(const ushort* __restrict__ S, ushort* ldsA,
                                             int node0, int tid, int N)
{
    #pragma unroll
    for (int i = 0; i < 4; ++i) {
        int chunk = tid + (i << 9);          // 0..2047
        int r = chunk >> 4, cin = chunk & 15;
        int g = node0 + r;
        uint4 v;
        if (g < N) v = *(const uint4*)(S + (size_t)g * 128 + (cin << 3));
        else       { v.x = 0; v.y = 0; v.z = 0; v.w = 0; }
        *(uint4*)((char*)ldsA + r * 256 + ((cin ^ (r & 7)) << 4)) = v;
    }
}

__global__ __launch_bounds__(512, 4) void out2_fused(
    const ushort* __restrict__ Sf, const ushort* __restrict__ Si,
    const ushort* __restrict__ CWimg, const float* __restrict__ cb,
    float* __restrict__ out, int N)
{
    __shared__ __align__(16) ushort ldsW[16384];
    __shared__ __align__(16) ushort ldsA[16384];
    int tid = threadIdx.x, lane = tid & 63, w = tid >> 6;
    int node0 = blockIdx.x << 7;
    f32x4 acc[8];
    #pragma unroll
    for (int i = 0; i < 8; ++i) acc[i] = f32x4{0.f, 0.f, 0.f, 0.f};
    #pragma unroll
    for (int pass = 0; pass < 2; ++pass) {
        if (pass) __syncthreads();
        stage_w(CWimg + (pass << 14), ldsW, tid);
        stage_a_bf16(pass ? Si : Sf, ldsA, node0, tid, N);
        __syncthreads();
        mfma_gemm_128(ldsA, ldsW, lane, w << 4, acc);
    }
    int l15 = lane & 15, lg = lane >> 4;
    #pragma unroll
    for (int ct = 0; ct < 8; ++ct) {
        int c = (ct << 4) + l15;
        float bb = cb[c];
        #pragma unroll
        for (int j = 0; j < 4; ++j) {
            int g = node0 + (w << 4) + (lg << 2) + j;
            if (g < N) out[(size_t)g * 128 + c] = acc[ct][j] + bb;
        }
    }
}

// ---------------- graph-level heads -> out1[128] ----------------
__global__ void final_kernel(const float* __restrict__ convsum,
    const float* __restrict__ mw1, const float* __restrict__ mb1,
    const float* __restrict__ mw2, const float* __restrict__ mb2,
    const float* __restrict__ iw1, const float* __restrict__ ib1,
    const float* __restrict__ iw2, const float* __restrict__ ib2,
    const float* __restrict__ cw, const float* __restrict__ cb,
    float* __restrict__ out1)
{
    __shared__ float x[384];
    __shared__ float t1[128];
    __shared__ float t2[128];
    __shared__ float g1[128];
    __shared__ float g2[128];
    int j = threadIdx.x;   // 128 threads
    x[j] = convsum[j]; x[128 + j] = convsum[128 + j]; x[256 + j] = convsum[256 + j];
    __syncthreads();
    float a = mb1[j];
    for (int k = 0; k < 384; ++k) a += x[k] * mw1[k * 128 + j];
    t1[j] = lrelu(a);
    float c = ib1[j];
    for (int k = 0; k < 384; ++k) c += x[256 + (k & 127)] * iw1[k * 128 + j];
    t2[j] = lrelu(c);
    __syncthreads();
    float b = mb2[j];
    float d = ib2[j];
    for (int k = 0; k < 128; ++k) {
        b += t1[k] * mw2[k * 128 + j];
        d += t2[k] * iw2[k * 128 + j];
    }
    g1[j] = b; g2[j] = d;
    __syncthreads();
    float e = cb[j];
    for (int k = 0; k < 128; ++k)
        e += g1[k] * cw[k * 128 + j] + g2[k] * cw[(128 + k) * 128 + j];
    out1[j] = e;
}

extern "C" void kernel_launch(void* const* d_in, const int* in_sizes, int n_in,
                              void* d_out, int out_size, void* d_ws, size_t ws_size,
                              hipStream_t stream)
{
    (void)n_in; (void)out_size; (void)ws_size;
    const int*   ops    = (const int*)d_in[0];
    const int*   params = (const int*)d_in[1];
    const int*   esrc   = (const int*)d_in[2];
    const int*   edst   = (const int*)d_in[3];
    const float* opT    = (const float*)d_in[4];
    const float* parT   = (const float*)d_in[5];
    const float* ow1    = (const float*)d_in[6];
    const float* ob1    = (const float*)d_in[7];
    const float* ow2    = (const float*)d_in[8];
    const float* ob2    = (const float*)d_in[9];
    const float* convw  = (const float*)d_in[10];
    const float* convb  = (const float*)d_in[11];
    const float* mw1    = (const float*)d_in[12];
    const float* mb1    = (const float*)d_in[13];
    const float* mw2    = (const float*)d_in[14];
    const float* mb2    = (const float*)d_in[15];
    const float* iw1    = (const float*)d_in[16];
    const float* ib1    = (const float*)d_in[17];
    const float* iw2    = (const float*)d_in[18];
    const float* ib2    = (const float*)d_in[19];
    const float* cw     = (const float*)d_in[20];
    const float* cb     = (const float*)d_in[21];

    const int N = in_sizes[0];      // 100000
    const int E = in_sizes[2];      // 1600000
    const int nb = (N + 511) >> ABITS;   // 196 bins per direction
    const size_t NP = (size_t)N * 128;

    // workspace layout (~162 MB)
    ushort* S0   = (ushort*)d_ws;                    // [N][128] bf16
    ushort* S1   = S0 + NP;
    ushort* S2   = S1 + NP;
    ushort* S3   = S2 + NP;
    ushort* Wt   = S3 + NP;                          // 6 * 16384 bf16 images
    float*  Atab = (float*)(Wt + 6 * 16384);         // 320*128 fp32
    float*  convsum = Atab + 320 * 128;              // 384 used, 512 reserved
    int*    gcur = (int*)(convsum + 512);            // 2*nb used, 512 reserved
    uint2*  binbuf = (uint2*)(gcur + 512);           // 2*nb*CAPB entries
    int*    csr_f = (int*)(binbuf + (size_t)2 * nb * CAPB);   // nb*CAPB
    int*    csr_i = csr_f + (size_t)nb * CAPB;
    int*    off_f = csr_i + (size_t)nb * CAPB;       // N each
    int*    cnt_f = off_f + N;
    int*    off_i = cnt_f + N;
    int*    cnt_i = off_i + N;

    float* out1 = (float*)d_out;
    float* out2 = out1 + 128;

    hipMemsetAsync(convsum, 0, sizeof(float) * 1024, stream);   // convsum + gcur

    tables_kernel<<<320, 128, 0, stream>>>(opT, parT, ow1, Atab);
    prep_w<<<384, 256, 0, stream>>>(convw, ow2, cw, Wt);
    binpass_kernel<<<(E + CHUNK - 1) / CHUNK, 256, 0, stream>>>(esrc, edst, E, nb, gcur, binbuf);
    csrpass_kernel<<<2 * nb, 256, 0, stream>>>(binbuf, gcur, nb, N,
                                               csr_f, off_f, cnt_f, csr_i, off_i, cnt_i);

    const int grid = (N + 127) / 128;
    opemb_fused<<<grid, 512, 0, stream>>>(ops, params, Atab, ob1, Wt + 3 * 16384, ob2, S0, S2, N);

    // layer i: fwd Sx->Sy (colsum), inv Sz->Sw  (merged, interleaved blocks)
    gin_fused2<<<2 * grid, 512, 0, stream>>>(S0, S1, S2, S3, Wt,             convb,
                                             csr_f, off_f, cnt_f, csr_i, off_i, cnt_i,
                                             convsum,       N);
    gin_fused2<<<2 * grid, 512, 0, stream>>>(S1, S0, S3, S2, Wt + 16384,     convb + 128,
                                             csr_f, off_f, cnt_f, csr_i, off_i, cnt_i,
                                             convsum + 128, N);
    gin_fused2<<<2 * grid, 512, 0, stream>>>(S0, S1, S2, S3, Wt + 2 * 16384, convb + 256,
                                             csr_f, off_f, cnt_f, csr_i, off_i, cnt_i,
                                             convsum + 256, N);

    final_kernel<<<1, 128, 0, stream>>>(convsum, mw1, mb1, mw2, mb2,
                                        iw1, ib1, iw2, ib2, cw, cb, out1);
    out2_fused<<<grid, 512, 0, stream>>>(S1, S3, Wt + 4 * 16384, cb, out2, N);
}

// Round 4
// 712.271 us; speedup vs baseline: 3.3945x; 1.3065x over previous
//
#include <hip/hip_runtime.h>

// SemaEmb GIN network — round 4: de-fused high-occupancy gather + streaming MFMA GEMM.
// N=100000, E=1600000, EMB=128, L=3, P=4.

typedef unsigned int  uint;
typedef unsigned short ushort;
typedef float  f32x4  __attribute__((ext_vector_type(4)));
typedef short  bf16x8 __attribute__((ext_vector_type(8)));

#define ABITS 9          // 512 nodes per bin
#define CAPB  12288      // entries per bin segment
#define CHUNK 2048       // edges per binpass block

__device__ __forceinline__ float lrelu(float x) { return x > 0.0f ? x : 0.01f * x; }
__device__ __forceinline__ ushort f2b(float x) {
    uint u = __float_as_uint(x);
    return (ushort)((u + 0x7fffu + ((u >> 16) & 1u)) >> 16);
}
__device__ __forceinline__ float lof(uint u) { return __uint_as_float(u << 16); }
__device__ __forceinline__ float hif(uint u) { return __uint_as_float(u & 0xffff0000u); }

// ---------------- fp32 folded tables: A[t*64+v][j] = emb_t[v] @ W1 block t ----------------
__global__ void tables_kernel(const float* __restrict__ opT, const float* __restrict__ parT,
                              const float* __restrict__ W1, float* __restrict__ A)
{
    int b = blockIdx.x;            // 0..319 : t*64+v
    int t = b >> 6, v = b & 63, j = threadIdx.x;
    const float* emb = (t == 0 ? opT : parT) + v * 128;
    const float* w = W1 + (size_t)t * 128 * 128;
    float acc = 0.f;
    for (int k = 0; k < 128; ++k) acc += emb[k] * w[k * 128 + j];
    A[(size_t)b * 128 + j] = acc;
}

// ---------------- bf16 transposed + pre-swizzled weight images ----------------
__global__ void prep_w(const float* __restrict__ convw, const float* __restrict__ ow2,
                       const float* __restrict__ cw, ushort* __restrict__ Wt)
{
    int t = blockIdx.x * 256 + threadIdx.x;     // 6 images * 16384
    int img = t >> 14, idx = t & 16383;
    int k = idx >> 7, c = idx & 127;
    const float* src;
    if (img < 3)      src = convw + img * 16384;
    else if (img == 3) src = ow2;
    else              src = cw + (img - 4) * 16384;
    float v = src[k * 128 + c];
    int byteoff = (img << 15) + (c << 8) + ((((k >> 3) ^ (c & 7)) << 4)) + ((k & 7) << 1);
    Wt[byteoff >> 1] = f2b(v);
}

// ---------------- CSR build pass A: bin edges by key>>ABITS (both directions) ----------------
__global__ __launch_bounds__(256) void binpass_kernel(
    const int* __restrict__ esrc, const int* __restrict__ edst, int E, int nb,
    int* __restrict__ gcur, uint2* __restrict__ binbuf)
{
    __shared__ int hist[448];
    __shared__ int lstart[448];
    __shared__ int gbase[448];
    __shared__ int lcur[448];
    __shared__ int gsum[8];
    __shared__ uint sKey[CHUNK * 2];
    __shared__ uint sPay[CHUNK * 2];
    __shared__ ushort sBin[CHUNK * 2];
    int tid = threadIdx.x, lane = tid & 63;
    int nb2 = nb * 2;

    for (int chunk = blockIdx.x; (size_t)chunk * CHUNK < (size_t)E; chunk += gridDim.x) {
        int base = chunk * CHUNK;
        int cnt = min(CHUNK, E - base);
        for (int i = tid; i < 448; i += 256) hist[i] = 0;
        __syncthreads();
        int s[8], d[8];
        #pragma unroll
        for (int i = 0; i < 8; ++i) {
            int idx = i * 256 + tid;
            if (idx < cnt) {
                s[i] = esrc[base + idx];
                d[i] = edst[base + idx];
                atomicAdd(&hist[d[i] >> ABITS], 1);
                atomicAdd(&hist[nb + (s[i] >> ABITS)], 1);
            } else s[i] = -1;
        }
        __syncthreads();
        #pragma unroll
        for (int k = 0; k < 2; ++k) {
            int idx = k * 256 + tid;
            int v = (idx < 448) ? hist[idx] : 0;
            int p = v;
            #pragma unroll
            for (int sh = 1; sh < 64; sh <<= 1) { int t = __shfl_up(p, sh, 64); if (lane >= sh) p += t; }
            if (idx < 448) {
                lstart[idx] = p - v;
                if (lane == 63) gsum[idx >> 6] = p;
            }
        }
        __syncthreads();
        if (tid == 0) { int run = 0; for (int g = 0; g < 7; ++g) { int t = gsum[g]; gsum[g] = run; run += t; } }
        __syncthreads();
        #pragma unroll
        for (int k = 0; k < 2; ++k) {
            int idx = k * 256 + tid;
            if (idx < 448) lstart[idx] += gsum[idx >> 6];
        }
        __syncthreads();
        for (int i = tid; i < nb2; i += 256) {
            int h = hist[i];
            gbase[i] = h ? atomicAdd(&gcur[i], h) : 0;
            lcur[i] = lstart[i];
        }
        __syncthreads();
        #pragma unroll
        for (int i = 0; i < 8; ++i) {
            if (s[i] >= 0) {
                int bf = d[i] >> ABITS;
                int p = atomicAdd(&lcur[bf], 1);
                sKey[p] = (uint)d[i]; sPay[p] = (uint)s[i]; sBin[p] = (ushort)bf;
                int bi = nb + (s[i] >> ABITS);
                int q = atomicAdd(&lcur[bi], 1);
                sKey[q] = (uint)s[i]; sPay[q] = (uint)d[i]; sBin[q] = (ushort)bi;
            }
        }
        __syncthreads();
        int total = 2 * cnt;
        for (int p = tid; p < total; p += 256) {
            int b = sBin[p];
            int pos = gbase[b] + (p - lstart[b]);
            if (pos < CAPB) binbuf[(size_t)b * CAPB + pos] = make_uint2(sKey[p], sPay[p]);
        }
        __syncthreads();
    }
}

// ---------------- CSR build pass B: per-bin CSR + off/cnt ----------------
__global__ __launch_bounds__(256) void csrpass_kernel(
    const uint2* __restrict__ binbuf, const int* __restrict__ gcur, int nb, int N,
    int* __restrict__ csr_f, int* __restrict__ off_f, int* __restrict__ cnt_f,
    int* __restrict__ csr_i, int* __restrict__ off_i, int* __restrict__ cnt_i)
{
    __shared__ int hist[512];
    __shared__ int loff[512];
    __shared__ int cur[512];
    __shared__ int gsum[8];
    int b = blockIdx.x;
    int dir = (b >= nb) ? 1 : 0;
    int binLocal = dir ? b - nb : b;
    int node0 = binLocal << ABITS;
    int nn = min(512, N - node0);
    int tid = threadIdx.x, lane = tid & 63;
    int total = min(gcur[b], CAPB);
    const uint2* seg = binbuf + (size_t)b * CAPB;
    int* csr = dir ? csr_i : csr_f;
    int* off = dir ? off_i : off_f;
    int* cnt = dir ? cnt_i : cnt_f;

    for (int i = tid; i < 512; i += 256) hist[i] = 0;
    __syncthreads();
    for (int e = tid; e < total; e += 256) {
        uint2 kp = seg[e];
        atomicAdd(&hist[kp.x - (uint)node0], 1);
    }
    __syncthreads();
    #pragma unroll
    for (int k = 0; k < 2; ++k) {
        int idx = k * 256 + tid;
        int v = hist[idx];
        int p = v;
        #pragma unroll
        for (int sh = 1; sh < 64; sh <<= 1) { int t = __shfl_up(p, sh, 64); if (lane >= sh) p += t; }
        loff[idx] = p - v;
        if (lane == 63) gsum[idx >> 6] = p;
    }
    __syncthreads();
    if (tid == 0) { int run = 0; for (int g = 0; g < 8; ++g) { int t = gsum[g]; gsum[g] = run; run += t; } }
    __syncthreads();
    #pragma unroll
    for (int k = 0; k < 2; ++k) {
        int idx = k * 256 + tid;
        loff[idx] += gsum[idx >> 6];
    }
    __syncthreads();
    int csrBase = binLocal * CAPB;
    for (int i = tid; i < 512; i += 256) {
        cur[i] = loff[i];
        if (i < nn) { off[node0 + i] = csrBase + loff[i]; cnt[node0 + i] = hist[i]; }
    }
    __syncthreads();
    int* csrSeg = csr + csrBase;
    for (int e = tid; e < total; e += 256) {
        uint2 kp = seg[e];
        int p = atomicAdd(&cur[kp.x - (uint)node0], 1);
        csrSeg[p] = (int)kp.y;
    }
}

// ---------------- standalone aggregation (both dirs): msg = self + mean(nbrs), bf16 ----------
__global__ __launch_bounds__(256, 8) void agg2_kernel(
    const ushort* __restrict__ Sf, const ushort* __restrict__ Si,
    const int* __restrict__ csr_f, const int* __restrict__ off_f, const int* __restrict__ cnt_f,
    const int* __restrict__ csr_i, const int* __restrict__ off_i, const int* __restrict__ cnt_i,
    ushort* __restrict__ msgf, ushort* __restrict__ msgi, int N)
{
    int gw = (blockIdx.x * 256 + threadIdx.x) >> 6;   // one wave per (node, dir)
    int lane = threadIdx.x & 63;
    int dir = 0, g = gw;
    if (g >= N) { dir = 1; g -= N; if (g >= N) return; }
    const uint* Sp = (const uint*)(dir ? Si : Sf);
    const int* csr = dir ? csr_i : csr_f;
    int off = (dir ? off_i : off_f)[g];
    int deg = (dir ? cnt_i : cnt_f)[g];

    float ax = 0.f, ay = 0.f;
    int d = 0;
    for (; d + 8 <= deg; d += 8) {
        int n0 = csr[off + d + 0], n1 = csr[off + d + 1];
        int n2 = csr[off + d + 2], n3 = csr[off + d + 3];
        int n4 = csr[off + d + 4], n5 = csr[off + d + 5];
        int n6 = csr[off + d + 6], n7 = csr[off + d + 7];
        uint v0 = Sp[(size_t)n0 * 64 + lane];
        uint v1 = Sp[(size_t)n1 * 64 + lane];
        uint v2 = Sp[(size_t)n2 * 64 + lane];
        uint v3 = Sp[(size_t)n3 * 64 + lane];
        uint v4 = Sp[(size_t)n4 * 64 + lane];
        uint v5 = Sp[(size_t)n5 * 64 + lane];
        uint v6 = Sp[(size_t)n6 * 64 + lane];
        uint v7 = Sp[(size_t)n7 * 64 + lane];
        ax += ((lof(v0) + lof(v1)) + (lof(v2) + lof(v3)))
            + ((lof(v4) + lof(v5)) + (lof(v6) + lof(v7)));
        ay += ((hif(v0) + hif(v1)) + (hif(v2) + hif(v3)))
            + ((hif(v4) + hif(v5)) + (hif(v6) + hif(v7)));
    }
    if (d + 4 <= deg) {
        int n0 = csr[off + d + 0], n1 = csr[off + d + 1];
        int n2 = csr[off + d + 2], n3 = csr[off + d + 3];
        uint v0 = Sp[(size_t)n0 * 64 + lane];
        uint v1 = Sp[(size_t)n1 * 64 + lane];
        uint v2 = Sp[(size_t)n2 * 64 + lane];
        uint v3 = Sp[(size_t)n3 * 64 + lane];
        ax += (lof(v0) + lof(v1)) + (lof(v2) + lof(v3));
        ay += (hif(v0) + hif(v1)) + (hif(v2) + hif(v3));
        d += 4;
    }
    for (; d < deg; ++d) {
        uint v = Sp[(size_t)csr[off + d] * 64 + lane];
        ax += lof(v); ay += hif(v);
    }
    float invd = 1.0f / fmaxf((float)deg, 1.0f);
    uint self = Sp[(size_t)g * 64 + lane];
    ax = lof(self) + ax * invd;
    ay = hif(self) + ay * invd;
    uint pk = (uint)f2b(ax) | ((uint)f2b(ay) << 16);
    ((uint*)(dir ? msgi : msgf))[(size_t)g * 64 + lane] = pk;
}

// ---------------- shared MFMA helpers ----------------
// A-tile/W-tile LDS layout: row r (256B); 16B chunk ch stored at ch^(r&7).
__device__ __forceinline__ void stage_w(const ushort* __restrict__ img, ushort* ldsW, int tid)
{
    const uint4* s = (const uint4*)img;
    uint4* d = (uint4*)ldsW;
    #pragma unroll
    for (int i = 0; i < 4; ++i) d[tid + (i << 9)] = s[tid + (i << 9)];
}

__device__ __forceinline__ void mfma_gemm_128(const ushort* ldsA, const ushort* ldsW,
                                              int lane, int row0, f32x4 acc[8])
{
    int l15 = lane & 15, lg = lane >> 4;
    int arow = row0 + l15;
    const char* Ab = (const char*)ldsA + arow * 256;
    int akey = (arow & 7) << 4;
    #pragma unroll
    for (int kk = 0; kk < 4; ++kk) {
        bf16x8 af = *(const bf16x8*)(Ab + ((((kk << 2) + lg) << 4) ^ akey));
        #pragma unroll
        for (int ct = 0; ct < 8; ++ct) {
            int c = (ct << 4) + l15;
            const char* Bb = (const char*)ldsW + c * 256;
            bf16x8 bf = *(const bf16x8*)(Bb + ((((kk << 2) + lg) << 4) ^ ((c & 7) << 4)));
            acc[ct] = __builtin_amdgcn_mfma_f32_16x16x32_bf16(af, bf, acc[ct], 0, 0, 0);
        }
    }
}

__device__ __forceinline__ void stage_a_bf16(const ushort* __restrict__ S, ushort* ldsA,
                                             int node0, int tid, int N)
{
    #pragma unroll
    for (int i = 0; i < 4; ++i) {
        int chunk = tid + (i << 9);          // 0..2047
        int r = chunk >> 4, cin = chunk & 15;
        int g = node0 + r;
        uint4 v;
        if (g < N) v = *(const uint4*)(S + (size_t)g * 128 + (cin << 3));
        else       { v.x = 0; v.y = 0; v.z = 0; v.w = 0; }
        *(uint4*)((char*)ldsA + r * 256 + ((cin ^ (r & 7)) << 4)) = v;
    }
}

// ---------------- GIN layer GEMM from msg (both dirs): lrelu(msg @ W + b) ----------------
__global__ __launch_bounds__(512, 4) void gemm2_kernel(
    const ushort* __restrict__ msgf, const ushort* __restrict__ msgi,
    ushort* __restrict__ Sf_out, ushort* __restrict__ Si_out,
    const ushort* __restrict__ Wimg, const float* __restrict__ bias,
    float* __restrict__ colsum, int N)
{
    __shared__ __align__(16) ushort ldsW[16384];
    __shared__ __align__(16) ushort ldsA[16384];
    __shared__ float ldsCS[128];
    int tid = threadIdx.x, lane = tid & 63, w = tid >> 6;
    bool fwd = (blockIdx.x & 1) == 0;
    int node0 = (blockIdx.x >> 1) << 7;
    const ushort* msg = fwd ? msgf : msgi;
    ushort* Sout = fwd ? Sf_out : Si_out;

    stage_w(Wimg, ldsW, tid);
    stage_a_bf16(msg, ldsA, node0, tid, N);
    if (fwd && tid < 128) ldsCS[tid] = 0.f;
    __syncthreads();

    f32x4 acc[8];
    #pragma unroll
    for (int i = 0; i < 8; ++i) acc[i] = f32x4{0.f, 0.f, 0.f, 0.f};
    mfma_gemm_128(ldsA, ldsW, lane, w << 4, acc);

    int l15 = lane & 15, lg = lane >> 4;
    #pragma unroll
    for (int ct = 0; ct < 8; ++ct) {
        int c = (ct << 4) + l15;
        float bb = bias[c];
        float csum = 0.f;
        #pragma unroll
        for (int j = 0; j < 4; ++j) {
            int g = node0 + (w << 4) + (lg << 2) + j;
            float o = lrelu(acc[ct][j] + bb);
            if (g < N) {
                Sout[(size_t)g * 128 + c] = f2b(o);
                csum += o;
            }
        }
        if (fwd) {
            csum += __shfl_xor(csum, 16);
            csum += __shfl_xor(csum, 32);
            if (lg == 0) atomicAdd(&ldsCS[c], csum);
        }
    }
    if (fwd) {
        __syncthreads();
        if (tid < 128) atomicAdd(&colsum[tid], ldsCS[tid]);
    }
}

// ---------------- op embedding MLP (tables -> lrelu -> @W2+b2), bf16 out x2 ----------------
__global__ __launch_bounds__(512, 4) void opemb_fused(
    const int* __restrict__ ops, const int* __restrict__ params,
    const float* __restrict__ Atab, const float* __restrict__ b1,
    const ushort* __restrict__ W2img, const float* __restrict__ b2,
    ushort* __restrict__ S0, ushort* __restrict__ S2, int N)
{
    __shared__ __align__(16) ushort ldsW[16384];
    __shared__ __align__(16) ushort ldsA[16384];
    int tid = threadIdx.x, lane = tid & 63, w = tid >> 6;
    int node0 = blockIdx.x << 7;

    stage_w(W2img, ldsW, tid);

    int r = tid >> 2, sub = tid & 3;      // 4 threads/row, 32 cols each
    int g = node0 + r;
    float4 acc4[8];
    if (g < N) {
        int op = ops[g];
        const float4* T = (const float4*)(Atab + ((size_t)op << 7) + (sub << 5));
        #pragma unroll
        for (int q = 0; q < 8; ++q) acc4[q] = T[q];
        #pragma unroll
        for (int p = 0; p < 4; ++p) {
            int pv = params[(g << 2) + p];
            const float4* Tp = (const float4*)(Atab + ((size_t)((p + 1) * 64 + pv) << 7) + (sub << 5));
            #pragma unroll
            for (int q = 0; q < 8; ++q) {
                float4 u = Tp[q];
                acc4[q].x += u.x; acc4[q].y += u.y; acc4[q].z += u.z; acc4[q].w += u.w;
            }
        }
        const float4* Bv = (const float4*)(b1 + (sub << 5));
        #pragma unroll
        for (int q = 0; q < 8; ++q) {
            float4 bb = Bv[q];
            acc4[q].x = lrelu(acc4[q].x + bb.x);
            acc4[q].y = lrelu(acc4[q].y + bb.y);
            acc4[q].z = lrelu(acc4[q].z + bb.z);
            acc4[q].w = lrelu(acc4[q].w + bb.w);
        }
    } else {
        #pragma unroll
        for (int q = 0; q < 8; ++q) acc4[q] = make_float4(0.f, 0.f, 0.f, 0.f);
    }
    int akey = r & 7;
    #pragma unroll
    for (int q2 = 0; q2 < 4; ++q2) {
        int ch = (sub << 2) + q2;
        float4 a = acc4[q2 * 2], b = acc4[q2 * 2 + 1];
        uint4 pk;
        pk.x = (uint)f2b(a.x) | ((uint)f2b(a.y) << 16);
        pk.y = (uint)f2b(a.z) | ((uint)f2b(a.w) << 16);
        pk.z = (uint)f2b(b.x) | ((uint)f2b(b.y) << 16);
        pk.w = (uint)f2b(b.z) | ((uint)f2b(b.w) << 16);
        *(uint4*)((char*)ldsA + r * 256 + ((ch ^ akey) << 4)) = pk;
    }
    __syncthreads();

    f32x4 acc[8];
    #pragma unroll
    for (int i = 0; i < 8; ++i) acc[i] = f32x4{0.f, 0.f, 0.f, 0.f};
    mfma_gemm_128(ldsA, ldsW, lane, w << 4, acc);

    int l15 = lane & 15, lg = lane >> 4;
    #pragma unroll
    for (int ct = 0; ct < 8; ++ct) {
        int c = (ct << 4) + l15;
        float bb = b2[c];
        #pragma unroll
        for (int j = 0; j < 4; ++j) {
            int gg = node0 + (w << 4) + (lg << 2) + j;
            if (gg < N) {
                ushort ob = f2b(acc[ct][j] + bb);     // no lrelu on layer 2
                S0[(size_t)gg * 128 + c] = ob;
                S2[(size_t)gg * 128 + c] = ob;
            }
        }
    }
}

// ---------------- out2 = [Sf | Si] @ comb_w + comb_b (fp32 out) ----------------
__global__ __launch_bounds__(512, 4) void out2_fused(
    const ushort* __restrict__ Sf, const ushort* __restrict__ Si,
    const ushort* __restrict__ CWimg, const float* __restrict__ cb,
    float* __restrict__ out, int N)
{
    __shared__ __align__(16) ushort ldsW[16384];
    __shared__ __align__(16) ushort ldsA[16384];
    int tid = threadIdx.x, lane = tid & 63, w = tid >> 6;
    int node0 = blockIdx.x << 7;
    f32x4 acc[8];
    #pragma unroll
    for (int i = 0; i < 8; ++i) acc[i] = f32x4{0.f, 0.f, 0.f, 0.f};
    #pragma unroll
    for (int pass = 0; pass < 2; ++pass) {
        if (pass) __syncthreads();
        stage_w(CWimg + (pass << 14), ldsW, tid);
        stage_a_bf16(pass ? Si : Sf, ldsA, node0, tid, N);
        __syncthreads();
        mfma_gemm_128(ldsA, ldsW, lane, w << 4, acc);
    }
    int l15 = lane & 15, lg = lane >> 4;
    #pragma unroll
    for (int ct = 0; ct < 8; ++ct) {
        int c = (ct << 4) + l15;
        float bb = cb[c];
        #pragma unroll
        for (int j = 0; j < 4; ++j) {
            int g = node0 + (w << 4) + (lg << 2) + j;
            if (g < N) out[(size_t)g * 128 + c] = acc[ct][j] + bb;
        }
    }
}

// ---------------- graph-level heads -> out1[128] ----------------
__global__ void final_kernel(const float* __restrict__ convsum,
    const float* __restrict__ mw1, const float* __restrict__ mb1,
    const float* __restrict__ mw2, const float* __restrict__ mb2,
    const float* __restrict__ iw1, const float* __restrict__ ib1,
    const float* __restrict__ iw2, const float* __restrict__ ib2,
    const float* __restrict__ cw, const float* __restrict__ cb,
    float* __restrict__ out1)
{
    __shared__ float x[384];
    __shared__ float t1[128];
    __shared__ float t2[128];
    __shared__ float g1[128];
    __shared__ float g2[128];
    int j = threadIdx.x;   // 128 threads
    x[j] = convsum[j]; x[128 + j] = convsum[128 + j]; x[256 + j] = convsum[256 + j];
    __syncthreads();
    float a = mb1[j];
    for (int k = 0; k < 384; ++k) a += x[k] * mw1[k * 128 + j];
    t1[j] = lrelu(a);
    float c = ib1[j];
    for (int k = 0; k < 384; ++k) c += x[256 + (k & 127)] * iw1[k * 128 + j];
    t2[j] = lrelu(c);
    __syncthreads();
    float b = mb2[j];
    float d = ib2[j];
    for (int k = 0; k < 128; ++k) {
        b += t1[k] * mw2[k * 128 + j];
        d += t2[k] * iw2[k * 128 + j];
    }
    g1[j] = b; g2[j] = d;
    __syncthreads();
    float e = cb[j];
    for (int k = 0; k < 128; ++k)
        e += g1[k] * cw[k * 128 + j] + g2[k] * cw[(128 + k) * 128 + j];
    out1[j] = e;
}

extern "C" void kernel_launch(void* const* d_in, const int* in_sizes, int n_in,
                              void* d_out, int out_size, void* d_ws, size_t ws_size,
                              hipStream_t stream)
{
    (void)n_in; (void)out_size; (void)ws_size;
    const int*   ops    = (const int*)d_in[0];
    const int*   params = (const int*)d_in[1];
    const int*   esrc   = (const int*)d_in[2];
    const int*   edst   = (const int*)d_in[3];
    const float* opT    = (const float*)d_in[4];
    const float* parT   = (const float*)d_in[5];
    const float* ow1    = (const float*)d_in[6];
    const float* ob1    = (const float*)d_in[7];
    const float* ow2    = (const float*)d_in[8];
    const float* ob2    = (const float*)d_in[9];
    const float* convw  = (const float*)d_in[10];
    const float* convb  = (const float*)d_in[11];
    const float* mw1    = (const float*)d_in[12];
    const float* mb1    = (const float*)d_in[13];
    const float* mw2    = (const float*)d_in[14];
    const float* mb2    = (const float*)d_in[15];
    const float* iw1    = (const float*)d_in[16];
    const float* ib1    = (const float*)d_in[17];
    const float* iw2    = (const float*)d_in[18];
    const float* ib2    = (const float*)d_in[19];
    const float* cw     = (const float*)d_in[20];
    const float* cb     = (const float*)d_in[21];

    const int N = in_sizes[0];      // 100000
    const int E = in_sizes[2];      // 1600000
    const int nb = (N + 511) >> ABITS;   // 196 bins per direction
    const size_t NP = (size_t)N * 128;

    // workspace layout (~162 MB)
    ushort* S0   = (ushort*)d_ws;                    // [N][128] bf16
    ushort* S1   = S0 + NP;
    ushort* S2   = S1 + NP;
    ushort* S3   = S2 + NP;
    ushort* Wt   = S3 + NP;                          // 6 * 16384 bf16 images
    float*  Atab = (float*)(Wt + 6 * 16384);         // 320*128 fp32
    float*  convsum = Atab + 320 * 128;              // 384 used, 512 reserved
    int*    gcur = (int*)(convsum + 512);            // 2*nb used, 512 reserved
    uint2*  binbuf = (uint2*)(gcur + 512);           // 2*nb*CAPB entries
    int*    csr_f = (int*)(binbuf + (size_t)2 * nb * CAPB);   // nb*CAPB
    int*    csr_i = csr_f + (size_t)nb * CAPB;
    int*    off_f = csr_i + (size_t)nb * CAPB;       // N each
    int*    cnt_f = off_f + N;
    int*    off_i = cnt_f + N;
    int*    cnt_i = off_i + N;

    float* out1 = (float*)d_out;
    float* out2 = out1 + 128;
    // msg buffers live in the (dead until the end) out2 region: 2 * N*128 bf16 = N*128 fp32
    ushort* MSGF = (ushort*)out2;
    ushort* MSGI = MSGF + NP;

    hipMemsetAsync(convsum, 0, sizeof(float) * 1024, stream);   // convsum + gcur

    tables_kernel<<<320, 128, 0, stream>>>(opT, parT, ow1, Atab);
    prep_w<<<384, 256, 0, stream>>>(convw, ow2, cw, Wt);
    binpass_kernel<<<(E + CHUNK - 1) / CHUNK, 256, 0, stream>>>(esrc, edst, E, nb, gcur, binbuf);
    csrpass_kernel<<<2 * nb, 256, 0, stream>>>(binbuf, gcur, nb, N,
                                               csr_f, off_f, cnt_f, csr_i, off_i, cnt_i);

    const int grid = (N + 127) / 128;
    opemb_fused<<<grid, 512, 0, stream>>>(ops, params, Atab, ob1, Wt + 3 * 16384, ob2, S0, S2, N);

    const int aggGrid = (2 * N + 3) / 4;   // one wave per (node, dir)
    // layer 0: fwd S0->S1 (colsum), inv S2->S3
    agg2_kernel<<<aggGrid, 256, 0, stream>>>(S0, S2, csr_f, off_f, cnt_f, csr_i, off_i, cnt_i, MSGF, MSGI, N);
    gemm2_kernel<<<2 * grid, 512, 0, stream>>>(MSGF, MSGI, S1, S3, Wt,             convb,       convsum,       N);
    // layer 1: fwd S1->S0, inv S3->S2
    agg2_kernel<<<aggGrid, 256, 0, stream>>>(S1, S3, csr_f, off_f, cnt_f, csr_i, off_i, cnt_i, MSGF, MSGI, N);
    gemm2_kernel<<<2 * grid, 512, 0, stream>>>(MSGF, MSGI, S0, S2, Wt + 16384,     convb + 128, convsum + 128, N);
    // layer 2: fwd S0->S1, inv S2->S3
    agg2_kernel<<<aggGrid, 256, 0, stream>>>(S0, S2, csr_f, off_f, cnt_f, csr_i, off_i, cnt_i, MSGF, MSGI, N);
    gemm2_kernel<<<2 * grid, 512, 0, stream>>>(MSGF, MSGI, S1, S3, Wt + 2 * 16384, convb + 256, convsum + 256, N);

    final_kernel<<<1, 128, 0, stream>>>(convsum, mw1, mb1, mw2, mb2,
                                        iw1, ib1, iw2, ib2, cw, cb, out1);
    out2_fused<<<grid, 512, 0, stream>>>(S1, S3, Wt + 4 * 16384, cb, out2, N);
}